// Round 2
// baseline (223.228 us; speedup 1.0000x reference)
//
#include <hip/hip_runtime.h>

// GridInterpolator: trilinear interpolation over 8 voxel grids, phased by grid.
// vox: [8, 96, 96, 96, 16] f32, gidx: [N,1] i32, pts: [N,3] f32 -> out: [N,16] f32
//
// 8 launches, one per grid g. Working set per launch = one grid (54 MiB) ->
// L3-resident -> each unique line fetched from HBM once.
//
// Wave structure: each wave owns 64 consecutive points. It ballots which of
// them belong to grid g, then processes the matches one at a time with ALL 64
// lanes: lane = corner_group(2 bits) * 16 + feature(4 bits). Each lane loads
// 2 z-adjacent corners for its (corner_group, feature), applies trilinear
// weights, then a 2-step butterfly shuffle sums over the 4 corner groups.
// Lanes 0..15 write the 16 output features (one 64-B store).

#define GDIM 96
#define NFEAT 16
#define NGRIDS 8

__global__ __launch_bounds__(256) void grid_interp_pass(
    const float* __restrict__ vox,
    const int*   __restrict__ gidx,
    const float* __restrict__ pts,
    float*       __restrict__ out,
    int n_pts, int g)
{
    const int lane  = threadIdx.x & 63;
    const int wavei = (blockIdx.x * (blockDim.x >> 6)) + (threadIdx.x >> 6);
    const int pbase = wavei * 64;
    if (pbase >= n_pts) return;

    const int p_lane = pbase + lane;
    const bool valid = (p_lane < n_pts);

    // per-lane preload: this lane's candidate point
    const int gv = valid ? gidx[p_lane] : -1;
    float plx = 0.f, ply = 0.f, plz = 0.f;
    if (valid) {
        plx = pts[p_lane * 3 + 0];
        ply = pts[p_lane * 3 + 1];
        plz = pts[p_lane * 3 + 2];
    }

    unsigned long long mask = __ballot(gv == g);

    const int cg = lane >> 4;      // corner group 0..3 : (ox, oy)
    const int f  = lane & 15;      // feature
    const int ox = cg & 1;
    const int oy = (cg >> 1) & 1;

    while (mask) {
        const int poff = __builtin_ctzll(mask);
        mask &= mask - 1;
        const int p = pbase + poff;

        // broadcast point coords from the owning lane
        const float px = __shfl(plx, poff, 64);
        const float py = __shfl(ply, poff, 64);
        const float pz = __shfl(plz, poff, 64);

        const float ux = (px + 1.0f) * 0.5f;
        const float uy = (py + 1.0f) * 0.5f;
        const float uz = (pz + 1.0f) * 0.5f;
        const bool inside = (ux >= 0.0f) & (ux <= 1.0f) &
                            (uy >= 0.0f) & (uy <= 1.0f) &
                            (uz >= 0.0f) & (uz <= 1.0f);

        const float sx = ux * (float)(GDIM - 1);
        const float sy = uy * (float)(GDIM - 1);
        const float sz = uz * (float)(GDIM - 1);
        const int bx = (int)sx, by = (int)sy, bz = (int)sz;
        const float fx = sx - (float)bx;
        const float fy = sy - (float)by;
        const float fz = sz - (float)bz;

        // clipped corner coords for this lane's corner group
        int cx = bx + ox; cx = cx < 0 ? 0 : (cx > GDIM - 1 ? GDIM - 1 : cx);
        int cy = by + oy; cy = cy < 0 ? 0 : (cy > GDIM - 1 ? GDIM - 1 : cy);
        int cz0 = bz;     cz0 = cz0 < 0 ? 0 : (cz0 > GDIM - 1 ? GDIM - 1 : cz0);
        int cz1 = bz + 1; cz1 = cz1 < 0 ? 0 : (cz1 > GDIM - 1 ? GDIM - 1 : cz1);

        const int cellbase = ((g * GDIM + cx) * GDIM + cy) * GDIM;
        const float v0 = vox[(cellbase + cz0) * NFEAT + f];
        const float v1 = vox[(cellbase + cz1) * NFEAT + f];

        const float wx  = ox ? fx : 1.0f - fx;
        const float wy  = oy ? fy : 1.0f - fy;
        const float wxy = wx * wy;
        float acc = wxy * fmaf(fz, v1, (1.0f - fz) * v0);

        // sum over the 4 corner groups (lanes f, f+16, f+32, f+48)
        acc += __shfl_xor(acc, 16, 64);
        acc += __shfl_xor(acc, 32, 64);

        if (lane < NFEAT) {
            out[p * NFEAT + lane] = inside ? acc : 0.0f;
        }
    }
}

extern "C" void kernel_launch(void* const* d_in, const int* in_sizes, int n_in,
                              void* d_out, int out_size, void* d_ws, size_t ws_size,
                              hipStream_t stream) {
    const float* vox  = (const float*)d_in[0];
    const int*   gidx = (const int*)  d_in[1];
    const float* pts  = (const float*)d_in[2];
    float*       outp = (float*)d_out;

    const int n_pts = in_sizes[1];                 // N
    const int threads = 256;                       // 4 waves = 256 points/block
    const int blocks  = (n_pts + 255) / 256;       // 4096 at N=1M

    for (int g = 0; g < NGRIDS; ++g) {
        grid_interp_pass<<<blocks, threads, 0, stream>>>(vox, gidx, pts, outp, n_pts, g);
    }
}